// Round 3
// baseline (580.284 us; speedup 1.0000x reference)
//
#include <hip/hip_runtime.h>

// CapsuleLayer dynamic routing, fp32, MI355X.
// Strategy: never materialize u_hat [32,2048,32,32]=256MiB. Recompute it in each
// of the 3 routing passes from W (128 MiB, L3-resident after pass 0).
// b-logits are reconstructed as dot(u_hat, v0[+v1]) so no b-state is stored.
// IC=16: 256 blocks (1/CU), atomic s-flush = 4.2M adds/pass.
// Flush uses unsafeAtomicAdd -> native global_atomic_add_f32 (a CAS loop under
// 128-way same-address contention would dominate the whole kernel).

#define B_TOT 32
#define NI    2048
#define DIN   16
#define NO    32
#define DOUT  32
#define IC    16    // i-values per block
#define BH    16    // b-values per block (2 blocks cover the batch)

// ws layout (float offsets)
#define S0_OFF 0
#define S1_OFF 32768
#define S2_OFF 65536
#define V0_OFF 98304
#define VS_OFF 99328

__device__ __forceinline__ void fma2(float2& a, float s, float2 w) {
    a.x = fmaf(s, w.x, a.x);
    a.y = fmaf(s, w.y, a.y);
}

__device__ __forceinline__ void atom_add_f32(float* p, float v) {
#if defined(__HIP_DEVICE_COMPILE__)
    unsafeAtomicAdd(p, v);   // native global_atomic_add_f32 on gfx950
#else
    atomicAdd(p, v);
#endif
}

template <int PASS>
__global__ __launch_bounds__(512, 1)
void caps_pass(const float* __restrict__ U, const float* __restrict__ W,
               const float* __restrict__ Vprev, float* __restrict__ Sout)
{
    const int t  = threadIdx.x;
    const int j  = t >> 4;          // 0..31 output capsule
    const int dp = t & 15;          // d-pair: d = 2dp, 2dp+1
    const int b0 = (blockIdx.x & 1) * BH;
    const int i0 = (blockIdx.x >> 1) * IC;

    __shared__ float lg[BH][NO];    // logits, then exp(logits)
    __shared__ float inv_sum[BH];

    float2 sacc[BH];
#pragma unroll
    for (int b = 0; b < BH; ++b) sacc[b] = make_float2(0.f, 0.f);

    // v to dot u_hat with (pass1: v0, pass2: v0+v1) — loop-invariant, hoisted.
    float2 vs[BH];
    if constexpr (PASS >= 1) {
#pragma unroll
        for (int b = 0; b < BH; ++b) {
            const float* vp = Vprev + ((b0 + b) * NO + j) * DOUT + 2 * dp;
            vs[b] = make_float2(vp[0], vp[1]);
        }
    }

    for (int ii = 0; ii < IC; ++ii) {
        const int i = i0 + ii;

        // W fragment for this thread: w2[c] = W[i, j, c, 2dp..2dp+1]
        float2 w2[DIN];
        const float* wp = W + ((size_t)(i * NO + j) * DIN) * DOUT + 2 * dp;
#pragma unroll
        for (int c = 0; c < DIN; ++c)
            w2[c] = *reinterpret_cast<const float2*>(wp + c * DOUT);

        float2 uh[BH];
#pragma unroll
        for (int b = 0; b < BH; ++b) {
            // wave-uniform address -> scalar-load candidate (s_load_dwordx16)
            const float* up = U + ((size_t)((b0 + b) * NI + i)) * DIN;
            const float4 ua = *reinterpret_cast<const float4*>(up);
            const float4 ub = *reinterpret_cast<const float4*>(up + 4);
            const float4 uc = *reinterpret_cast<const float4*>(up + 8);
            const float4 ud = *reinterpret_cast<const float4*>(up + 12);
            float2 acc = make_float2(0.f, 0.f);
            fma2(acc, ua.x, w2[0]);  fma2(acc, ua.y, w2[1]);
            fma2(acc, ua.z, w2[2]);  fma2(acc, ua.w, w2[3]);
            fma2(acc, ub.x, w2[4]);  fma2(acc, ub.y, w2[5]);
            fma2(acc, ub.z, w2[6]);  fma2(acc, ub.w, w2[7]);
            fma2(acc, uc.x, w2[8]);  fma2(acc, uc.y, w2[9]);
            fma2(acc, uc.z, w2[10]); fma2(acc, uc.w, w2[11]);
            fma2(acc, ud.x, w2[12]); fma2(acc, ud.y, w2[13]);
            fma2(acc, ud.z, w2[14]); fma2(acc, ud.w, w2[15]);
            uh[b] = acc;

            if constexpr (PASS >= 1) {
                // logit partial: uh . v_prev  (this thread's 2 d's)
                float p = acc.x * vs[b].x + acc.y * vs[b].y;
                // sum over the 16 dp-lanes (same j)
                p += __shfl_xor(p, 1);
                p += __shfl_xor(p, 2);
                p += __shfl_xor(p, 4);
                p += __shfl_xor(p, 8);
                if (dp == 0) lg[b][j] = p;
            } else {
                // c is uniform 1/32: accumulate directly (scaled at the end)
                sacc[b].x += acc.x;
                sacc[b].y += acc.y;
            }
        }

        if constexpr (PASS >= 1) {
            __syncthreads();
            // softmax over j for each of the BH rows; thread t -> (row, jj)
            {
                const int row = t >> 5;   // 0..15
                const int jj  = t & 31;
                float e = __expf(lg[row][jj]);
                float s = e;
                s += __shfl_xor(s, 1);
                s += __shfl_xor(s, 2);
                s += __shfl_xor(s, 4);
                s += __shfl_xor(s, 8);
                s += __shfl_xor(s, 16);
                lg[row][jj] = e;          // own cell only: safe in-place
                if (jj == 0) inv_sum[row] = 1.0f / s;
            }
            __syncthreads();

#pragma unroll
            for (int b = 0; b < BH; ++b) {
                const float cc = lg[b][j] * inv_sum[b];
                sacc[b].x = fmaf(cc, uh[b].x, sacc[b].x);
                sacc[b].y = fmaf(cc, uh[b].y, sacc[b].y);
            }
            __syncthreads();  // lg reused next i
        }
    }

#pragma unroll
    for (int b = 0; b < BH; ++b) {
        float sx = sacc[b].x, sy = sacc[b].y;
        if constexpr (PASS == 0) { sx *= (1.0f / NO); sy *= (1.0f / NO); }
        float* sp = Sout + ((b0 + b) * NO + j) * DOUT + 2 * dp;
        atom_add_f32(sp,     sx);
        atom_add_f32(sp + 1, sy);
    }
}

// v = squash(s) [+ Vadd]; one thread per (b,j) row of 32 d's.
__global__ void caps_squash(const float* __restrict__ S,
                            const float* __restrict__ Vadd,
                            float* __restrict__ Out)
{
    const int cell = blockIdx.x * blockDim.x + threadIdx.x;  // b*32 + j
    if (cell >= B_TOT * NO) return;
    const float* sp = S + (size_t)cell * DOUT;
    float v[DOUT];
    float n2 = 0.f;
#pragma unroll
    for (int d = 0; d < DOUT; ++d) { v[d] = sp[d]; n2 = fmaf(v[d], v[d], n2); }
    const float scale = n2 / (1.0f + n2) / sqrtf(n2 + 1e-7f);
    float* op = Out + (size_t)cell * DOUT;
    if (Vadd != nullptr) {
        const float* vp = Vadd + (size_t)cell * DOUT;
#pragma unroll
        for (int d = 0; d < DOUT; ++d) op[d] = scale * v[d] + vp[d];
    } else {
#pragma unroll
        for (int d = 0; d < DOUT; ++d) op[d] = scale * v[d];
    }
}

extern "C" void kernel_launch(void* const* d_in, const int* in_sizes, int n_in,
                              void* d_out, int out_size, void* d_ws, size_t ws_size,
                              hipStream_t stream)
{
    const float* U = (const float*)d_in[0];   // [32, 2048, 16]
    const float* W = (const float*)d_in[1];   // [2048, 32, 16, 32]
    float* out = (float*)d_out;               // [32, 32, 32]
    float* ws  = (float*)d_ws;

    float* s0   = ws + S0_OFF;
    float* s1   = ws + S1_OFF;
    float* s2   = ws + S2_OFF;
    float* v0   = ws + V0_OFF;
    float* vsum = ws + VS_OFF;

    // zero the atomic s-accumulators (ws is poisoned 0xAA before every call)
    hipMemsetAsync(ws, 0, (size_t)3 * 32768 * sizeof(float), stream);

    const dim3 grid((NI / IC) * 2);   // 256 blocks: i-chunk x b-half (1 per CU)
    const dim3 blk(512);

    caps_pass<0><<<grid, blk, 0, stream>>>(U, W, nullptr, s0);
    caps_squash<<<8, 128, 0, stream>>>(s0, nullptr, v0);      // v0 = squash(s0)
    caps_pass<1><<<grid, blk, 0, stream>>>(U, W, v0, s1);
    caps_squash<<<8, 128, 0, stream>>>(s1, v0, vsum);         // vsum = v0 + squash(s1)
    caps_pass<2><<<grid, blk, 0, stream>>>(U, W, vsum, s2);
    caps_squash<<<8, 128, 0, stream>>>(s2, nullptr, out);     // out = squash(s2)
}